// Round 7
// baseline (39.203 us; speedup 1.0000x reference)
//
#include <hip/hip_runtime.h>
#include <math.h>

#define NL 28
#define H 1024
#define W 1024
#define HW (H * W)
#define ROWS 3            // output rows per block
#define CHUNK 504         // output px per block (2 px/thread, 252 threads active)
#define XROW 512          // staged x window per band (2 x 1KB global_load_lds)
#define MROW 1152         // padded mask row: 64 guard | 1024 data | 64 guard
#define MGUARD 64
#define MB_ROWS (ROWS + 1)

// 8B vector, 4B-alignment-safe -> LDS loads become ds_read2_b32 (one instr).
typedef float f2 __attribute__((ext_vector_type(2), aligned(4)));

typedef __attribute__((address_space(1))) const void GV;
typedef __attribute__((address_space(3))) void LV;
__device__ __forceinline__ void gl_lds16(const float* g, float* l) {
    __builtin_amdgcn_global_load_lds((GV*)g, (LV*)l, 16, 0, 0);
}

// out[Y,X] = sum_l mask[Y-dy_l, X-dx_l] * x[l, Y-dy_l, X-dx_l]
// Per block: stage 4 full guard-padded mask rows once + per-y a 512-float x
// window per band via global_load_lds; compute 2 px/thread from LDS.
// OOB rows/cols resolve to zeroed mask guards -> no per-pixel compares.
__global__ __launch_bounds__(256)
void cassi_v7(const float* __restrict__ x, const float* __restrict__ mask,
              const float* __restrict__ phi_deg, const float* __restrict__ s_nom,
              float* __restrict__ out, int out_size)
{
    __shared__ float xbuf[NL][XROW];       // 57.3 KB
    __shared__ float mbuf[MB_ROWS][MROW];  // 18.4 KB
    __shared__ int s_dx[NL], s_dy[NL], s_xs[NL];
    __shared__ unsigned s_pack[NL];
    __shared__ int s_geom[6];

    const int tid = threadIdx.x;
    const int lane = tid & 63;
    const int wid = tid >> 6;

    // ---- offsets + per-band pack: wave 0, lane-parallel ----
    if (tid < 64) {
        float phi = phi_deg[0] * 0.017453292519943295f;
        float c = cosf(phi), sn = sinf(phi);
        float s = (tid < NL) ? s_nom[tid] : 0.f;
        float dxv = s * c, dyv = s * sn;
        float dxm = (tid < NL) ? dxv : 3.0e38f;
        float dym = (tid < NL) ? dyv : 3.0e38f;
        for (int d = 1; d < 64; d <<= 1) {
            dxm = fminf(dxm, __shfl_xor(dxm, d, 64));
            dym = fminf(dym, __shfl_xor(dym, d, 64));
        }
        int dxi = (tid < NL) ? (int)rintf(dxv - dxm) : 0;
        int dyi = (tid < NL) ? (int)rintf(dyv - dym) : 0;
        int dxmax = dxi, dymax = dyi;
        for (int d = 1; d < 64; d <<= 1) {
            dxmax = max(dxmax, __shfl_xor(dxmax, d, 64));
            dymax = max(dymax, __shfl_xor(dymax, d, 64));
        }
        int Wp = W + dxmax;
        int Hp = out_size / Wp;
        int nchunk = (Wp + CHUNK - 1) / CHUNK;
        if (tid < NL) { s_dx[tid] = dxi; s_dy[tid] = dyi; }
        if (tid == 0) {
            s_geom[0] = Wp; s_geom[1] = Hp; s_geom[2] = nchunk;
            s_geom[3] = (Hp + ROWS - 1) / ROWS;  // nY
            s_geom[4] = dxmax; s_geom[5] = dymax;
        }
        int Ygrp = blockIdx.x / nchunk;
        int X0 = (blockIdx.x - Ygrp * nchunk) * CHUNK;
        if (tid < NL) {
            int xs = (X0 - dxi) & ~3;            // 16B-aligned staging start
            xs = min(max(xs, 0), W - XROW);
            s_xs[tid] = xs;
            unsigned xib = (unsigned)(X0 - dxi - xs) & 511u;  // mod-512 wrap
            int P = MGUARD + X0 - dxi + (1 - dyi) * MROW;     // mi = P + y*MROW + t
            P = max(P, 0);
            s_pack[tid] = ((unsigned)P << 9) | xib;
        }
    }
    __syncthreads();

    const int Wp = s_geom[0], Hp = s_geom[1], nchunk = s_geom[2], nY = s_geom[3];
    const bool fast = (s_geom[5] <= 1) && (s_geom[4] <= MGUARD);

    if (!fast) {
        // Safety net for unexpected geometry: grid-stride checked gather.
        for (int i = blockIdx.x * 256 + tid; i < out_size; i += gridDim.x * 256) {
            int Y = i / Wp, X = i - Y * Wp;
            float a = 0.f;
            for (int l = 0; l < NL; ++l) {
                int h = Y - s_dy[l], w = X - s_dx[l];
                if ((unsigned)h < (unsigned)H && (unsigned)w < (unsigned)W) {
                    int p = h * W + w;
                    a = fmaf(mask[p], x[(size_t)l * HW + p], a);
                }
            }
            out[i] = a;
        }
        return;
    }

    const int Ygrp = blockIdx.x / nchunk;
    if (Ygrp >= nY) return;  // over-provisioned grid
    const int X0 = (blockIdx.x - Ygrp * nchunk) * CHUNK;
    const int Y0 = Ygrp * ROWS;

    // Hoist pack words into registers (28 VGPRs, statically indexed below).
    unsigned pks[NL];
#pragma unroll
    for (int l = 0; l < NL; ++l) pks[l] = s_pack[l];

    // ---- prolog staging: mask rows Y0-1..Y0+2 (wave wid -> row wid) ----
    {
        int g = Y0 - 1 + wid;
        if ((unsigned)g < (unsigned)H) {
            const float* src = mask + (size_t)g * W + lane * 4;
#pragma unroll
            for (int k = 0; k < 4; ++k)
                gl_lds16(src + k * 256, &mbuf[wid][MGUARD + k * 256]);
        } else {
            for (int k = lane; k < 1024; k += 64) mbuf[wid][MGUARD + k] = 0.f;
        }
        mbuf[wid][lane] = 0.f;                 // left guard
        mbuf[wid][MGUARD + 1024 + lane] = 0.f; // right guard
    }
    // ---- x row Y0: 7 bands per wave, 2 x 1KB each ----
#pragma unroll
    for (int j = 0; j < 7; ++j) {
        int l = wid * 7 + j;
        int srow = min(max(Y0 - s_dy[l], 0), H - 1);  // clamped; zero mask row kills bad rows
        const float* src = x + (size_t)l * HW + (size_t)srow * W + s_xs[l] + lane * 4;
        gl_lds16(src, &xbuf[l][0]);
        gl_lds16(src + 256, &xbuf[l][256]);
    }
    __syncthreads();  // drains vmcnt: staged data visible

    const float* mflat = &mbuf[0][0];
    const int t2 = tid * 2;
    // Clamp out-of-chunk threads to px 0 (discarded) so LDS indices stay in-bounds.
    const int t2e = (t2 < CHUNK && X0 + t2 < Wp) ? t2 : 0;

#pragma unroll
    for (int y = 0; y < ROWS; ++y) {
        int Y = Y0 + y;
        if (Y >= Hp) break;  // block-uniform

        f2 acc = {0.f, 0.f};
#pragma unroll
        for (int l = 0; l < NL; ++l) {
            unsigned pk = pks[l];
            int xi = (int)(((pk & 511u) + (unsigned)t2e) & 511u);
            int mi = (int)(pk >> 9) + y * MROW + t2e;
            f2 xv = *(const f2*)&xbuf[l][xi];   // ds_read2_b32
            f2 mv = *(const f2*)&mflat[mi];     // ds_read2_b32 (guards zero OOB cols)
            acc += xv * mv;
        }

        int X = X0 + t2;
        if (t2 < CHUNK && X < Wp) {
            float* o = out + (size_t)Y * Wp + X;
            if (X + 1 < Wp) *(f2*)o = acc;
            else o[0] = acc.x;
        }

        if (y + 1 >= ROWS || Y + 1 >= Hp) break;  // block-uniform
        __syncthreads();  // all reads of xbuf done before restage
        int Yn = Y + 1;
#pragma unroll
        for (int j = 0; j < 7; ++j) {
            int l = wid * 7 + j;
            int srow = min(max(Yn - s_dy[l], 0), H - 1);
            const float* src = x + (size_t)l * HW + (size_t)srow * W + s_xs[l] + lane * 4;
            gl_lds16(src, &xbuf[l][0]);
            gl_lds16(src + 256, &xbuf[l][256]);
        }
        __syncthreads();  // staged row visible
    }
}

extern "C" void kernel_launch(void* const* d_in, const int* in_sizes, int n_in,
                              void* d_out, int out_size, void* d_ws, size_t ws_size,
                              hipStream_t stream) {
    const float* x = (const float*)d_in[0];      // [1, 28, 1024, 1024]
    const float* mask = (const float*)d_in[1];   // [1024, 1024]
    const float* phi = (const float*)d_in[2];    // [1]
    const float* s_nom = (const float*)d_in[3];  // [28]
    float* out = (float*)d_out;                  // [1, Hp, Wp]

    // Host doesn't know Hp/Wp; bound: Hp <= out/W (Wp>=W), Wp <= out/H (Hp>=H).
    int rowsBound = out_size / W;
    int colsBound = out_size / H;
    int blocks = ((rowsBound + ROWS) / ROWS + 1) * ((colsBound + CHUNK) / CHUNK + 1);
    cassi_v7<<<blocks, 256, 0, stream>>>(x, mask, phi, s_nom, out, out_size);
}

// Round 8
// 31.337 us; speedup vs baseline: 1.2510x; 1.2510x over previous
//
#include <hip/hip_runtime.h>
#include <math.h>

#define NL 28
#define H 1024
#define W 1024
#define HW (H * W)
#define GB 4              // bands per group (1 band per wave)
#define NG 7              // groups (NG*GB == NL)
#define BROW 1152         // padded row: 64 guard | 1024 data | 64 guard
#define GUARD 64

// 8B vector, 4B-alignment-safe -> ds_read2_b32.
typedef float f2 __attribute__((ext_vector_type(2), aligned(4)));

typedef __attribute__((address_space(1))) const void GV;
typedef __attribute__((address_space(3))) void LV;
__device__ __forceinline__ void gl_lds16(const float* g, float* l) {
    __builtin_amdgcn_global_load_lds((GV*)g, (LV*)l, 16, 0, 0);
}

// out[Y,X] = sum_l mask[Y-dy_l, X-dx_l] * x[l, Y-dy_l, X-dx_l]
// One block per output row Y, full width. Each x row is staged into LDS
// exactly once globally (zero overfetch). 2-phase double-buffered pipeline:
// stage group g+1 (global_load_lds, no dest VGPRs) while computing group g;
// counted drain at iteration end (T3-minimum, cdna guide §5.5).
// Guard-padded mask rows (zeros) absorb all OOB rows/cols -> no edge paths.
__global__ __launch_bounds__(256)
void cassi_v8(const float* __restrict__ x, const float* __restrict__ mask,
              const float* __restrict__ phi_deg, const float* __restrict__ s_nom,
              float* __restrict__ out, int out_size)
{
    __shared__ float xbuf[2][GB][BROW];   // 36.9 KB, double-buffered x rows
    __shared__ float mbuf[2][BROW];       // 9.2 KB, mask rows Y, Y-1 (guarded)
    __shared__ int s_dx[NL], s_dy[NL];
    __shared__ unsigned s_pk[NL];         // (moff<<16) | (GUARD - dx)
    __shared__ int s_geom[4];             // Wp, Hp, dxmax, dymax

    const int tid = threadIdx.x;
    const int lane = tid & 63;
    const int wid = tid >> 6;

    // ---- offsets: wave 0, lane-parallel (float math, validated r1-r7) ----
    if (tid < 64) {
        float phi = phi_deg[0] * 0.017453292519943295f;
        float c = cosf(phi), sn = sinf(phi);
        float s = (tid < NL) ? s_nom[tid] : 0.f;
        float dxv = s * c, dyv = s * sn;
        float dxm = (tid < NL) ? dxv : 3.0e38f;
        float dym = (tid < NL) ? dyv : 3.0e38f;
        for (int d = 1; d < 64; d <<= 1) {
            dxm = fminf(dxm, __shfl_xor(dxm, d, 64));
            dym = fminf(dym, __shfl_xor(dym, d, 64));
        }
        int dxi = (tid < NL) ? (int)rintf(dxv - dxm) : 0;
        int dyi = (tid < NL) ? (int)rintf(dyv - dym) : 0;
        int dxmax = dxi, dymax = dyi;
        for (int d = 1; d < 64; d <<= 1) {
            dxmax = max(dxmax, __shfl_xor(dxmax, d, 64));
            dymax = max(dymax, __shfl_xor(dymax, d, 64));
        }
        if (tid < NL) {
            s_dx[tid] = dxi;
            s_dy[tid] = dyi;
            int moff = dyi * BROW + GUARD - dxi;            // mbuf flat base
            s_pk[tid] = ((unsigned)moff << 16) | (unsigned)(GUARD - dxi);
        }
        if (tid == 0) {
            int Wp = W + dxmax;
            s_geom[0] = Wp;
            s_geom[1] = out_size / Wp;   // Hp (exact)
            s_geom[2] = dxmax;
            s_geom[3] = dymax;
        }
    }
    __syncthreads();

    const int Wp = s_geom[0], Hp = s_geom[1];
    const int Y = blockIdx.x;
    const bool fast = (s_geom[3] <= 1) && (s_geom[2] <= GUARD);

    if (!fast) {
        // Safety net for unexpected geometry: grid-stride checked gather.
        for (int i = blockIdx.x * 256 + tid; i < out_size; i += gridDim.x * 256) {
            int Yk = i / Wp, Xk = i - Yk * Wp;
            float a = 0.f;
            for (int l = 0; l < NL; ++l) {
                int h = Yk - s_dy[l], w = Xk - s_dx[l];
                if ((unsigned)h < (unsigned)H && (unsigned)w < (unsigned)W) {
                    int p = h * W + w;
                    a = fmaf(mask[p], x[(size_t)l * HW + p], a);
                }
            }
            out[i] = a;
        }
        return;
    }
    if (Y >= Hp) return;  // over-provisioned grid (uniform exit, no barriers yet)

    // Hoist per-band packs into 28 VGPRs (statically indexed below).
    unsigned pk[NL];
#pragma unroll
    for (int l = 0; l < NL; ++l) pk[l] = s_pk[l];

    // ---- prologue: mask rows (waves 0-1) + x group 0 (all waves) ----
    if (wid < 2) {
        int g = Y - wid;
        float* dst = &mbuf[wid][GUARD];
        if ((unsigned)g < (unsigned)H) {
            const float* src = mask + (size_t)g * W + lane * 4;
            gl_lds16(src, dst);
            gl_lds16(src + 256, dst + 256);
            gl_lds16(src + 512, dst + 512);
            gl_lds16(src + 768, dst + 768);
        } else {
            for (int k = lane; k < 1024; k += 64) dst[k] = 0.f;  // OOB row -> zeros
        }
    }
    {   // zero guards: 2 rows x 128 guard floats, 1 per thread
        int r = tid >> 7, c0 = tid & 127;
        int c = (c0 < GUARD) ? c0 : (1024 + c0);
        mbuf[r][c] = 0.f;
    }
    {   // x group 0: wave wid stages band wid's row (4 KB = 4 x 1KB)
        int dy = s_dy[wid];
        int srow = min(max(Y - dy, 0), H - 1);  // clamp; zeroed mask row kills OOB
        const float* src = x + (size_t)wid * HW + (size_t)srow * W + lane * 4;
        float* dst = &xbuf[0][wid][GUARD];
        gl_lds16(src, dst);
        gl_lds16(src + 256, dst + 256);
        gl_lds16(src + 512, dst + 512);
        gl_lds16(src + 768, dst + 768);
    }
    __syncthreads();  // drains vmcnt + lgkm: mask + group 0 visible

    // Effective pixel indices (junk lanes clamped to 0; stores guarded later).
    int Xe0 = (2 * tid + 1 < Wp) ? 2 * tid : 0;
    int Xe1 = (2 * tid + 512 + 1 < Wp) ? 2 * tid + 512 : 0;
    int Xe2 = (2 * tid + 1024 + 1 < Wp) ? 2 * tid + 1024 : 0;

    f2 acc0 = {0.f, 0.f}, acc1 = {0.f, 0.f}, acc2 = {0.f, 0.f};
    const float* xf = &xbuf[0][0][0];
    const float* mf = &mbuf[0][0];

#pragma unroll
    for (int g = 0; g < NG; ++g) {
        // Stage group g+1 into buf[(g+1)&1]. Safe: its last readers (compute
        // of group g-1) finished before the barrier that ended iteration g-1.
        if (g < NG - 1) {
            int l = (g + 1) * GB + wid;
            int dy = s_dy[l];
            int srow = min(max(Y - dy, 0), H - 1);
            const float* src = x + (size_t)l * HW + (size_t)srow * W + lane * 4;
            float* dst = &xbuf[(g + 1) & 1][wid][GUARD];
            gl_lds16(src, dst);
            gl_lds16(src + 256, dst + 256);
            gl_lds16(src + 512, dst + 512);
            gl_lds16(src + 768, dst + 768);
        }
        // Compute group g from buf[g&1] (overlaps the staging above).
#pragma unroll
        for (int w = 0; w < GB; ++w) {
            const int l = g * GB + w;
            unsigned p = pk[l];
            const int xo = (int)(p & 0xffffu) + ((g & 1) * GB + w) * BROW;
            const int mo = (int)(p >> 16);
            {
                f2 xv = *(const f2*)&xf[xo + Xe0];
                f2 mv = *(const f2*)&mf[mo + Xe0];
                acc0 += xv * mv;
            }
            {
                f2 xv = *(const f2*)&xf[xo + Xe1];
                f2 mv = *(const f2*)&mf[mo + Xe1];
                acc1 += xv * mv;
            }
            {
                f2 xv = *(const f2*)&xf[xo + Xe2];
                f2 mv = *(const f2*)&mf[mo + Xe2];
                acc2 += xv * mv;
            }
        }
        // Drain this wave's staging loads, then sync (T3-minimum schedule).
        asm volatile("s_waitcnt vmcnt(0)" ::: "memory");
        __builtin_amdgcn_s_barrier();
    }

    // ---- store row ----
    float* orow = out + (size_t)Y * Wp;
    {
        int X = 2 * tid;
        if (X + 1 < Wp) *(f2*)(orow + X) = acc0;
        else if (X < Wp) orow[X] = acc0.x;
    }
    {
        int X = 2 * tid + 512;
        if (X + 1 < Wp) *(f2*)(orow + X) = acc1;
        else if (X < Wp) orow[X] = acc1.x;
    }
    {
        int X = 2 * tid + 1024;
        if (X + 1 < Wp) *(f2*)(orow + X) = acc2;
        else if (X < Wp) orow[X] = acc2.x;
    }
}

extern "C" void kernel_launch(void* const* d_in, const int* in_sizes, int n_in,
                              void* d_out, int out_size, void* d_ws, size_t ws_size,
                              hipStream_t stream) {
    const float* x = (const float*)d_in[0];      // [1, 28, 1024, 1024]
    const float* mask = (const float*)d_in[1];   // [1024, 1024]
    const float* phi = (const float*)d_in[2];    // [1]
    const float* s_nom = (const float*)d_in[3];  // [28]
    float* out = (float*)d_out;                  // [1, Hp, Wp]

    // One block per output row; Hp <= out_size/W (since Wp >= W).
    const int blocks = out_size / W + 2;
    cassi_v8<<<blocks, 256, 0, stream>>>(x, mask, phi, s_nom, out, out_size);
}

// Round 10
// 30.950 us; speedup vs baseline: 1.2667x; 1.0125x over previous
//
#include <hip/hip_runtime.h>
#include <math.h>

#define NL 28
#define H 1024
#define W 1024
#define HW (H * W)
#define GB 4              // bands per group (1 band per wave)
#define NG 7              // groups (NG*GB == NL)
#define NBUF 3            // x-row buffers (2-deep prefetch)
#define BROW 1152         // padded row: 64 guard | 1024 data | 64 guard
#define GUARD 64

// 8B vector, 4B-alignment-safe -> ds_read2_b32.
typedef float f2 __attribute__((ext_vector_type(2), aligned(4)));

typedef __attribute__((address_space(1))) const void GV;
typedef __attribute__((address_space(3))) void LV;
__device__ __forceinline__ void gl_lds16(const float* g, float* l) {
    __builtin_amdgcn_global_load_lds((GV*)g, (LV*)l, 16, 0, 0);
}

// out[Y,X] = sum_l mask[Y-dy_l, X-dx_l] * x[l, Y-dy_l, X-dx_l]
// One block per output row Y. Each x row staged into LDS exactly once
// globally. T3+T4 schedule: 3 buffers, 2-deep prefetch, counted vmcnt(4) at
// iteration end -- next group's loads stay in flight ACROSS the barrier.
// v10 fix: xbuf guard columns are READ (left-edge pixels: xo+Xe lands in
// [GUARD-dx, GUARD)) but were never written -> leftover LDS NaN * mask-guard
// 0 = NaN (v9 fail; v8 passed only by data-placement luck). Zero them once.
__global__ __launch_bounds__(256)
void cassi_v10(const float* __restrict__ x, const float* __restrict__ mask,
               const float* __restrict__ phi_deg, const float* __restrict__ s_nom,
               float* __restrict__ out, int out_size)
{
    __shared__ float xbuf[NBUF][GB][BROW];  // 55.3 KB
    __shared__ float mbuf[2][BROW];         // 9.2 KB (mask rows Y, Y-1, guarded)
    __shared__ int s_dx[NL], s_dy[NL];
    __shared__ unsigned s_pk[NL];           // (moff<<16) | (GUARD - dx)
    __shared__ int s_geom[4];               // Wp, Hp, dxmax, dymax

    const int tid = threadIdx.x;
    const int lane = tid & 63;
    const int wid = tid >> 6;

    // ---- offsets: wave 0, lane-parallel ----
    if (tid < 64) {
        float phi = phi_deg[0] * 0.017453292519943295f;
        float c = cosf(phi), sn = sinf(phi);
        float s = (tid < NL) ? s_nom[tid] : 0.f;
        float dxv = s * c, dyv = s * sn;
        float dxm = (tid < NL) ? dxv : 3.0e38f;
        float dym = (tid < NL) ? dyv : 3.0e38f;
        for (int d = 1; d < 64; d <<= 1) {
            dxm = fminf(dxm, __shfl_xor(dxm, d, 64));
            dym = fminf(dym, __shfl_xor(dym, d, 64));
        }
        int dxi = (tid < NL) ? (int)rintf(dxv - dxm) : 0;
        int dyi = (tid < NL) ? (int)rintf(dyv - dym) : 0;
        int dxmax = dxi, dymax = dyi;
        for (int d = 1; d < 64; d <<= 1) {
            dxmax = max(dxmax, __shfl_xor(dxmax, d, 64));
            dymax = max(dymax, __shfl_xor(dymax, d, 64));
        }
        if (tid < NL) {
            s_dx[tid] = dxi;
            s_dy[tid] = dyi;
            int moff = dyi * BROW + GUARD - dxi;
            s_pk[tid] = ((unsigned)moff << 16) | (unsigned)(GUARD - dxi);
        }
        if (tid == 0) {
            int Wp = W + dxmax;
            s_geom[0] = Wp;
            s_geom[1] = out_size / Wp;   // Hp (exact)
            s_geom[2] = dxmax;
            s_geom[3] = dymax;
        }
    }
    __syncthreads();

    const int Wp = s_geom[0], Hp = s_geom[1];
    const int Y = blockIdx.x;
    const bool fast = (s_geom[3] <= 1) && (s_geom[2] <= GUARD);

    if (!fast) {
        // Safety net for unexpected geometry: grid-stride checked gather.
        for (int i = blockIdx.x * 256 + tid; i < out_size; i += gridDim.x * 256) {
            int Yk = i / Wp, Xk = i - Yk * Wp;
            float a = 0.f;
            for (int l = 0; l < NL; ++l) {
                int h = Yk - s_dy[l], w = Xk - s_dx[l];
                if ((unsigned)h < (unsigned)H && (unsigned)w < (unsigned)W) {
                    int p = h * W + w;
                    a = fmaf(mask[p], x[(size_t)l * HW + p], a);
                }
            }
            out[i] = a;
        }
        return;
    }
    if (Y >= Hp) return;  // uniform exit before any raw barrier

    // Hoist per-band packs into 28 VGPRs (statically indexed below).
    unsigned pk[NL];
#pragma unroll
    for (int l = 0; l < NL; ++l) pk[l] = s_pk[l];

    // ---- prologue ----
    // Zero xbuf guard columns (READ by edge pixels, never staged): 12 rows x
    // 128 floats. Disjoint from the [GUARD, GUARD+1024) staging region.
    {
        float* xflat = &xbuf[0][0][0];
#pragma unroll
        for (int j = 0; j < (NBUF * GB * 2 * GUARD) / 256; ++j) {
            int e = j * 256 + tid;
            int row = e >> 7;
            int c0 = e & 127;
            int c = (c0 < GUARD) ? c0 : (1024 + c0);
            xflat[row * BROW + c] = 0.f;
        }
    }
    // Mask rows Y (wave 0) and Y-1 (wave 1), guard-padded.
    if (wid < 2) {
        int g = Y - wid;
        float* dst = &mbuf[wid][GUARD];
        if ((unsigned)g < (unsigned)H) {
            const float* src = mask + (size_t)g * W + lane * 4;
            gl_lds16(src, dst);
            gl_lds16(src + 256, dst + 256);
            gl_lds16(src + 512, dst + 512);
            gl_lds16(src + 768, dst + 768);
        } else {
            for (int k = lane; k < 1024; k += 64) dst[k] = 0.f;  // OOB row -> zeros
        }
    }
    {   // zero mbuf guards: 2 rows x 128 guard floats, 1 per thread (ds_write)
        int r = tid >> 7, c0 = tid & 127;
        int c = (c0 < GUARD) ? c0 : (1024 + c0);
        mbuf[r][c] = 0.f;
    }
#pragma unroll
    for (int g0 = 0; g0 < 2; ++g0) {  // stage x groups 0,1 (wave wid -> band)
        int l = g0 * GB + wid;
        int srow = min(max(Y - s_dy[l], 0), H - 1);  // clamp; zero mask row kills OOB
        const float* src = x + (size_t)l * HW + (size_t)srow * W + lane * 4;
        float* dst = &xbuf[g0][wid][GUARD];
        gl_lds16(src, dst);
        gl_lds16(src + 256, dst + 256);
        gl_lds16(src + 512, dst + 512);
        gl_lds16(src + 768, dst + 768);
    }
    // Drain mask + group 0 (leave group 1's 4 loads in flight), drain ds_writes.
    asm volatile("s_waitcnt vmcnt(4) lgkmcnt(0)" ::: "memory");
    __builtin_amdgcn_s_barrier();

    // Effective pixel indices (junk lanes clamped to 0; stores guarded later).
    int Xe0 = (2 * tid + 1 < Wp) ? 2 * tid : 0;
    int Xe1 = (2 * tid + 512 + 1 < Wp) ? 2 * tid + 512 : 0;
    int Xe2 = (2 * tid + 1024 + 1 < Wp) ? 2 * tid + 1024 : 0;

    f2 acc0 = {0.f, 0.f}, acc1 = {0.f, 0.f}, acc2 = {0.f, 0.f};
    const float* xf = &xbuf[0][0][0];
    const float* mf = &mbuf[0][0];

#pragma unroll
    for (int g = 0; g < NG; ++g) {
        // Stage group g+2 into buf[(g+2)%3]. Its previous tenant (group g-1)
        // was fully read before the lgkmcnt(0)+barrier that ended iter g-1.
        if (g + 2 < NG) {
            int l = (g + 2) * GB + wid;
            int srow = min(max(Y - s_dy[l], 0), H - 1);
            const float* src = x + (size_t)l * HW + (size_t)srow * W + lane * 4;
            float* dst = &xbuf[(g + 2) % NBUF][wid][GUARD];
            gl_lds16(src, dst);
            gl_lds16(src + 256, dst + 256);
            gl_lds16(src + 512, dst + 512);
            gl_lds16(src + 768, dst + 768);
        }
        // Compute group g from buf[g%3] (overlaps staging above + in-flight g+1).
#pragma unroll
        for (int w = 0; w < GB; ++w) {
            const int l = g * GB + w;
            unsigned p = pk[l];
            const int xo = (int)(p & 0xffffu) + ((g % NBUF) * GB + w) * BROW;
            const int mo = (int)(p >> 16);
            {
                f2 xv = *(const f2*)&xf[xo + Xe0];
                f2 mv = *(const f2*)&mf[mo + Xe0];
                acc0 += xv * mv;
            }
            {
                f2 xv = *(const f2*)&xf[xo + Xe1];
                f2 mv = *(const f2*)&mf[mo + Xe1];
                acc1 += xv * mv;
            }
            {
                f2 xv = *(const f2*)&xf[xo + Xe2];
                f2 mv = *(const f2*)&mf[mo + Xe2];
                acc2 += xv * mv;
            }
        }
        // Counted drain (T4): require group g+1 landed; keep g+2 in flight.
        // lgkmcnt(0): no wave crosses the barrier with pending ds_reads of the
        // buffer that iter g+1's staging will overwrite.
        if (g + 2 < NG) {
            asm volatile("s_waitcnt vmcnt(4) lgkmcnt(0)" ::: "memory");
            __builtin_amdgcn_s_barrier();
        } else if (g + 1 < NG) {
            asm volatile("s_waitcnt vmcnt(0) lgkmcnt(0)" ::: "memory");
            __builtin_amdgcn_s_barrier();
        }
    }

    // ---- store row ----
    float* orow = out + (size_t)Y * Wp;
    {
        int X = 2 * tid;
        if (X + 1 < Wp) *(f2*)(orow + X) = acc0;
        else if (X < Wp) orow[X] = acc0.x;
    }
    {
        int X = 2 * tid + 512;
        if (X + 1 < Wp) *(f2*)(orow + X) = acc1;
        else if (X < Wp) orow[X] = acc1.x;
    }
    {
        int X = 2 * tid + 1024;
        if (X + 1 < Wp) *(f2*)(orow + X) = acc2;
        else if (X < Wp) orow[X] = acc2.x;
    }
}

extern "C" void kernel_launch(void* const* d_in, const int* in_sizes, int n_in,
                              void* d_out, int out_size, void* d_ws, size_t ws_size,
                              hipStream_t stream) {
    const float* x = (const float*)d_in[0];      // [1, 28, 1024, 1024]
    const float* mask = (const float*)d_in[1];   // [1024, 1024]
    const float* phi = (const float*)d_in[2];    // [1]
    const float* s_nom = (const float*)d_in[3];  // [28]
    float* out = (float*)d_out;                  // [1, Hp, Wp]

    // One block per output row; Hp <= out_size/W (since Wp >= W).
    const int blocks = out_size / W + 2;
    cassi_v10<<<blocks, 256, 0, stream>>>(x, mask, phi, s_nom, out, out_size);
}

// Round 11
// 28.545 us; speedup vs baseline: 1.3734x; 1.0843x over previous
//
#include <hip/hip_runtime.h>
#include <math.h>

#define NL 28
#define H 1024
#define W 1024
#define HW (H * W)
#define BROW 1152         // padded row: 64 guard | 1024 data | 64 guard
#define GUARD 64
#define WBANDS 7          // bands per wave (4 waves x 7 = 28)
#define NBUF 3            // per-wave x buffers (2-deep prefetch)
#define WREG (NBUF * BROW)  // per-wave LDS floats (3456)
#define NPASS 9           // 9 x 128 px passes cover Wp <= 1152

// 8B vector, 4B-alignment-safe -> ds_read2_b32.
typedef float f2 __attribute__((ext_vector_type(2), aligned(4)));

typedef __attribute__((address_space(1))) const void GV;
typedef __attribute__((address_space(3))) void LV;
__device__ __forceinline__ void gl_lds16(const float* g, float* l) {
    __builtin_amdgcn_global_load_lds((GV*)g, (LV*)l, 16, 0, 0);
}

// out[Y,X] = sum_l mask[Y-dy_l, X-dx_l] * x[l, Y-dy_l, X-dx_l]
// One block per output row. BARRIER-FREE main loop: wave w owns bands
// [7w, 7w+7), stages them into its PRIVATE LDS buffers with a per-wave
// counted-vmcnt depth-2 pipeline (vmcnt is per-wave), and accumulates
// partial sums for the FULL row. Waves sync only twice (mask ready,
// final 4-way partial reduction). This removes the 7 per-iteration
// collective barriers that coupled all waves to the slowest HBM return
// (v8-v10 plateau at ~31us vs ~20us HBM floor).
__global__ __launch_bounds__(256)
void cassi_v11(const float* __restrict__ x, const float* __restrict__ mask,
               const float* __restrict__ phi_deg, const float* __restrict__ s_nom,
               float* __restrict__ out, int out_size)
{
    __shared__ float lds[4 * WREG + 2 * BROW];  // 4 wave regions + 2 mask rows = 63 KB

    const int tid = threadIdx.x;
    const int lane = tid & 63;
    const int wid = tid >> 6;

    // ---- offsets: computed redundantly by EVERY wave (no broadcast barrier) ----
    float phi = phi_deg[0] * 0.017453292519943295f;
    float c = cosf(phi), sn = sinf(phi);
    float s = (lane < NL) ? s_nom[lane] : 0.f;
    float dxv = s * c, dyv = s * sn;
    float dxm = (lane < NL) ? dxv : 3.0e38f;
    float dym = (lane < NL) ? dyv : 3.0e38f;
    for (int d = 1; d < 64; d <<= 1) {
        dxm = fminf(dxm, __shfl_xor(dxm, d, 64));
        dym = fminf(dym, __shfl_xor(dym, d, 64));
    }
    int dxi = (lane < NL) ? (int)rintf(dxv - dxm) : 0;
    int dyi = (lane < NL) ? (int)rintf(dyv - dym) : 0;
    int dxmax = dxi, dymax = dyi;
    for (int d = 1; d < 64; d <<= 1) {
        dxmax = max(dxmax, __shfl_xor(dxmax, d, 64));
        dymax = max(dymax, __shfl_xor(dymax, d, 64));
    }
    const int Wp = W + dxmax;
    const int Hp = out_size / Wp;

    if (!(dymax <= 1 && dxmax <= GUARD)) {
        // Self-contained checked fallback (never taken for bench geometry).
        for (int i = blockIdx.x * 256 + tid; i < out_size; i += gridDim.x * 256) {
            int Yk = i / Wp, Xk = i - Yk * Wp;
            float a = 0.f;
            for (int l = 0; l < NL; ++l) {
                float sl = s_nom[l];
                int dx = (int)rintf(sl * c - dxm);
                int dy = (int)rintf(sl * sn - dym);
                int h = Yk - dy, w = Xk - dx;
                if ((unsigned)h < (unsigned)H && (unsigned)w < (unsigned)W) {
                    int p = h * W + w;
                    a = fmaf(mask[p], x[(size_t)l * HW + p], a);
                }
            }
            out[i] = a;
        }
        return;
    }

    const int Y = blockIdx.x;
    if (Y >= Hp) return;  // uniform exit before any barrier

    float* xw = &lds[wid * WREG];     // this wave's 3 private row buffers
    float* mb = &lds[4 * WREG];       // shared mask rows [2][BROW]

    // Zero own xbuf guard columns (read by edge pixels; never staged).
#pragma unroll
    for (int b = 0; b < NBUF; ++b) {
        xw[b * BROW + lane] = 0.f;
        xw[b * BROW + GUARD + 1024 + lane] = 0.f;
    }
    // Mask rows: wave 0 -> row Y, wave 1 -> row Y-1 (guard-padded; OOB -> zeros).
    if (wid < 2) {
        int g = Y - wid;
        float* mrow = &mb[wid * BROW];
        if ((unsigned)g < (unsigned)H) {
            const float* src = mask + (size_t)g * W + lane * 4;
            gl_lds16(src,       mrow + GUARD);
            gl_lds16(src + 256, mrow + GUARD + 256);
            gl_lds16(src + 512, mrow + GUARD + 512);
            gl_lds16(src + 768, mrow + GUARD + 768);
            mrow[lane] = 0.f;
            mrow[GUARD + 1024 + lane] = 0.f;
        } else {
            for (int k = lane; k < BROW; k += 64) mrow[k] = 0.f;
        }
    }
    // Stage own bands 0,1 (4 x 1KB gl_lds each).
#pragma unroll
    for (int j = 0; j < 2; ++j) {
        int l = wid * WBANDS + j;
        int dyj = __shfl(dyi, l, 64);
        int srow = min(max(Y - dyj, 0), H - 1);  // clamp; zeroed mask row kills OOB
        const float* src = x + (size_t)l * HW + (size_t)srow * W + lane * 4;
        float* dst = xw + j * BROW + GUARD;
        gl_lds16(src, dst);
        gl_lds16(src + 256, dst + 256);
        gl_lds16(src + 512, dst + 512);
        gl_lds16(src + 768, dst + 768);
    }
    // Waves 0/1: vmcnt(8) drains exactly the mask loads (bands 0,1 stay in
    // flight). Waves 2/3: no-op. lgkmcnt(0) publishes guard ds_writes.
    asm volatile("s_waitcnt vmcnt(8) lgkmcnt(0)" ::: "memory");
    __builtin_amdgcn_s_barrier();   // the ONLY pre-loop barrier (mask ready)

    // Hoisted clamped pixel offsets (band-independent): te[p] = 2*pixel index.
    int te[NPASS];
#pragma unroll
    for (int p = 0; p < NPASS; ++p) {
        int t = p * 128 + 2 * lane;
        te[p] = (t < Wp) ? t : 0;
    }

    f2 acc[NPASS];
#pragma unroll
    for (int p = 0; p < NPASS; ++p) acc[p] = f2{0.f, 0.f};

    // ---- barrier-free per-wave pipeline over 7 bands, depth 2 ----
#pragma unroll
    for (int j = 0; j < WBANDS; ++j) {
        if (j + 2 < WBANDS) {  // stage band j+2 into private buf (j+2)%3
            int l = wid * WBANDS + j + 2;
            int dyj = __shfl(dyi, l, 64);
            int srow = min(max(Y - dyj, 0), H - 1);
            const float* src = x + (size_t)l * HW + (size_t)srow * W + lane * 4;
            float* dst = xw + ((j + 2) % NBUF) * BROW + GUARD;
            gl_lds16(src, dst);
            gl_lds16(src + 256, dst + 256);
            gl_lds16(src + 512, dst + 512);
            gl_lds16(src + 768, dst + 768);
        }
        // Counted per-wave wait: band j landed; deeper prefetch stays in flight.
        if (j + 2 < WBANDS)      asm volatile("s_waitcnt vmcnt(8)" ::: "memory");
        else if (j + 1 < WBANDS) asm volatile("s_waitcnt vmcnt(4)" ::: "memory");
        else                     asm volatile("s_waitcnt vmcnt(0)" ::: "memory");

        int l = wid * WBANDS + j;
        int dxj = __shfl(dxi, l, 64);
        int dyj = __shfl(dyi, l, 64);
        const float* xb = xw + (j % NBUF) * BROW + GUARD - dxj;
        const float* mrow = mb + dyj * BROW + GUARD - dxj;
#pragma unroll
        for (int p = 0; p < NPASS; ++p) {
            f2 xv = *(const f2*)&xb[te[p]];     // ds_read2_b32
            f2 mv = *(const f2*)&mrow[te[p]];   // ds_read2_b32
            acc[p] += xv * mv;
        }
        // Own ds_reads of buf j%3 must finish before iter j+1 overwrites it
        // (stage target (j+3)%3 == j%3). Wave-local, cheap.
        asm volatile("s_waitcnt lgkmcnt(0)" ::: "memory");
        __builtin_amdgcn_sched_barrier(0);
    }

    // ---- partials -> own region (bands done; other waves never read it) ----
#pragma unroll
    for (int p = 0; p < NPASS; ++p) {
        int t = p * 128 + 2 * lane;
        if (t + 1 < Wp)      *(f2*)&xw[t] = acc[p];
        else if (t < Wp)     xw[t] = acc[p].x;   // odd-Wp tail (not hit here)
    }
    asm volatile("s_waitcnt lgkmcnt(0)" ::: "memory");
    __builtin_amdgcn_s_barrier();   // partials visible

    // ---- 4-way reduce + store ----
    float* orow = out + (size_t)Y * Wp;
#pragma unroll
    for (int q = 0; q < 3; ++q) {
        int t = 2 * (tid + q * 256);
        if (t + 1 < Wp) {
            f2 v = *(const f2*)&lds[0 * WREG + t];
            v += *(const f2*)&lds[1 * WREG + t];
            v += *(const f2*)&lds[2 * WREG + t];
            v += *(const f2*)&lds[3 * WREG + t];
            *(f2*)&orow[t] = v;
        } else if (t < Wp) {
            orow[t] = lds[0 * WREG + t] + lds[1 * WREG + t]
                    + lds[2 * WREG + t] + lds[3 * WREG + t];
        }
    }
}

extern "C" void kernel_launch(void* const* d_in, const int* in_sizes, int n_in,
                              void* d_out, int out_size, void* d_ws, size_t ws_size,
                              hipStream_t stream) {
    const float* x = (const float*)d_in[0];      // [1, 28, 1024, 1024]
    const float* mask = (const float*)d_in[1];   // [1024, 1024]
    const float* phi = (const float*)d_in[2];    // [1]
    const float* s_nom = (const float*)d_in[3];  // [28]
    float* out = (float*)d_out;                  // [1, Hp, Wp]

    // One block per output row; Hp <= out_size/W (since Wp >= W).
    const int blocks = out_size / W + 2;
    cassi_v11<<<blocks, 256, 0, stream>>>(x, mask, phi, s_nom, out, out_size);
}

// Round 12
// 26.958 us; speedup vs baseline: 1.4542x; 1.0589x over previous
//
#include <hip/hip_runtime.h>
#include <math.h>

#define NL 28
#define H 1024
#define W 1024
#define HW (H * W)
#define BROW 1152         // padded row: 64 guard | 1024 data | 64 guard
#define GUARD 64
#define NWAVE 2           // waves per block
#define WBANDS 14         // bands per wave (2 x 14 = 28)
#define NBUF 3            // per-wave x buffers (depth-2 prefetch)
#define WREG (NBUF * BROW)  // per-wave LDS floats (3456)
#define NPASS 9           // 9 x 128 px passes cover Wp <= 1152

// 8B vector, 4B-alignment-safe -> ds_read2_b32.
typedef float f2 __attribute__((ext_vector_type(2), aligned(4)));

typedef __attribute__((address_space(1))) const void GV;
typedef __attribute__((address_space(3))) void LV;
__device__ __forceinline__ void gl_lds16(const float* g, float* l) {
    __builtin_amdgcn_global_load_lds((GV*)g, (LV*)l, 16, 0, 0);
}

// out[Y,X] = sum_l mask[Y-dy_l, X-dx_l] * x[l, Y-dy_l, X-dx_l]
// One block per output row; BARRIER-FREE per-wave band pipelines (v11).
// v12: 2 waves x 14 bands (was 4x7) -> LDS 63->36 KB -> 4 resident
// blocks/CU (was 2). Same waves/CU and in-flight bytes, but 4 independent
// block timelines overlap prologue/drain/epilogue stalls, pipeline drain
// amortized over 14 bands, and the final reduce is 2-way instead of 4-way.
__global__ __launch_bounds__(128, 2)
void cassi_v12(const float* __restrict__ x, const float* __restrict__ mask,
               const float* __restrict__ phi_deg, const float* __restrict__ s_nom,
               float* __restrict__ out, int out_size)
{
    __shared__ float lds[NWAVE * WREG + 2 * BROW];  // 36 KB

    const int tid = threadIdx.x;
    const int lane = tid & 63;
    const int wid = tid >> 6;

    // ---- offsets: computed redundantly by every wave (no broadcast sync) ----
    float phi = phi_deg[0] * 0.017453292519943295f;
    float c = cosf(phi), sn = sinf(phi);
    float s = (lane < NL) ? s_nom[lane] : 0.f;
    float dxv = s * c, dyv = s * sn;
    float dxm = (lane < NL) ? dxv : 3.0e38f;
    float dym = (lane < NL) ? dyv : 3.0e38f;
    for (int d = 1; d < 64; d <<= 1) {
        dxm = fminf(dxm, __shfl_xor(dxm, d, 64));
        dym = fminf(dym, __shfl_xor(dym, d, 64));
    }
    int dxi = (lane < NL) ? (int)rintf(dxv - dxm) : 0;
    int dyi = (lane < NL) ? (int)rintf(dyv - dym) : 0;
    int dxmax = dxi, dymax = dyi;
    for (int d = 1; d < 64; d <<= 1) {
        dxmax = max(dxmax, __shfl_xor(dxmax, d, 64));
        dymax = max(dymax, __shfl_xor(dymax, d, 64));
    }
    const int Wp = W + dxmax;
    const int Hp = out_size / Wp;

    if (!(dymax <= 1 && dxmax <= GUARD)) {
        // Self-contained checked fallback (never taken for bench geometry).
        for (int i = blockIdx.x * 128 + tid; i < out_size; i += gridDim.x * 128) {
            int Yk = i / Wp, Xk = i - Yk * Wp;
            float a = 0.f;
            for (int l = 0; l < NL; ++l) {
                float sl = s_nom[l];
                int dx = (int)rintf(sl * c - dxm);
                int dy = (int)rintf(sl * sn - dym);
                int h = Yk - dy, w = Xk - dx;
                if ((unsigned)h < (unsigned)H && (unsigned)w < (unsigned)W) {
                    int p = h * W + w;
                    a = fmaf(mask[p], x[(size_t)l * HW + p], a);
                }
            }
            out[i] = a;
        }
        return;
    }

    const int Y = blockIdx.x;
    if (Y >= Hp) return;  // uniform exit before any barrier

    float* xw = &lds[wid * WREG];        // this wave's 3 private row buffers
    float* mb = &lds[NWAVE * WREG];      // shared mask rows [2][BROW]

    // Per-band constants in statically-indexed register arrays.
    int xo_[WBANDS], mo_[WBANDS], sr_[WBANDS];
#pragma unroll
    for (int j = 0; j < WBANDS; ++j) {
        int l = wid * WBANDS + j;
        int dxj = __shfl(dxi, l, 64);
        int dyj = __shfl(dyi, l, 64);
        xo_[j] = (j % NBUF) * BROW + GUARD - dxj;
        mo_[j] = dyj * BROW + GUARD - dxj;
        sr_[j] = min(max(Y - dyj, 0), H - 1);  // clamp; zero mask row kills OOB
    }

    // Zero own xbuf guard columns (read by edge pixels; never staged).
#pragma unroll
    for (int b = 0; b < NBUF; ++b) {
        xw[b * BROW + lane] = 0.f;
        xw[b * BROW + GUARD + 1024 + lane] = 0.f;
    }
    // Mask rows: wave 0 -> row Y, wave 1 -> row Y-1 (guard-padded; OOB -> zeros).
    {
        int g = Y - wid;
        float* mrow = &mb[wid * BROW];
        if ((unsigned)g < (unsigned)H) {
            const float* src = mask + (size_t)g * W + lane * 4;
            gl_lds16(src,       mrow + GUARD);
            gl_lds16(src + 256, mrow + GUARD + 256);
            gl_lds16(src + 512, mrow + GUARD + 512);
            gl_lds16(src + 768, mrow + GUARD + 768);
            mrow[lane] = 0.f;
            mrow[GUARD + 1024 + lane] = 0.f;
        } else {
            for (int k = lane; k < BROW; k += 64) mrow[k] = 0.f;
        }
    }
    // Stage own bands 0,1 (4 x 1KB gl_lds each).
#pragma unroll
    for (int j = 0; j < 2; ++j) {
        int l = wid * WBANDS + j;
        const float* src = x + (size_t)l * HW + (size_t)sr_[j] * W + lane * 4;
        float* dst = xw + j * BROW + GUARD;
        gl_lds16(src, dst);
        gl_lds16(src + 256, dst + 256);
        gl_lds16(src + 512, dst + 512);
        gl_lds16(src + 768, dst + 768);
    }
    // vmcnt(8): drains exactly the 4 mask loads (own bands 0,1 stay in
    // flight); lgkmcnt(0) publishes guard ds_writes.
    asm volatile("s_waitcnt vmcnt(8) lgkmcnt(0)" ::: "memory");
    __builtin_amdgcn_s_barrier();   // the ONLY pre-loop barrier (mask ready)

    // Clamped pixel offsets (band-independent). Clamp keeps mo_+te within the
    // mb region (right guard absorbs the tail) -- also bounds-safety.
    int te[NPASS];
#pragma unroll
    for (int p = 0; p < NPASS; ++p) {
        int t = p * 128 + 2 * lane;
        te[p] = (t < Wp) ? t : 0;
    }

    f2 acc[NPASS];
#pragma unroll
    for (int p = 0; p < NPASS; ++p) acc[p] = f2{0.f, 0.f};

    // ---- barrier-free per-wave pipeline over 14 bands, depth 2 ----
#pragma unroll
    for (int j = 0; j < WBANDS; ++j) {
        if (j + 2 < WBANDS) {  // stage band j+2 into private buf (j+2)%3
            int l = wid * WBANDS + j + 2;
            const float* src = x + (size_t)l * HW + (size_t)sr_[j + 2] * W + lane * 4;
            float* dst = xw + ((j + 2) % NBUF) * BROW + GUARD;
            gl_lds16(src, dst);
            gl_lds16(src + 256, dst + 256);
            gl_lds16(src + 512, dst + 512);
            gl_lds16(src + 768, dst + 768);
        }
        // Counted per-wave wait: band j landed; deeper prefetch in flight.
        if (j + 2 < WBANDS)      asm volatile("s_waitcnt vmcnt(8)" ::: "memory");
        else if (j + 1 < WBANDS) asm volatile("s_waitcnt vmcnt(4)" ::: "memory");
        else                     asm volatile("s_waitcnt vmcnt(0)" ::: "memory");

        const float* xb = xw + xo_[j];
        const float* mrow = mb + mo_[j];
#pragma unroll
        for (int p = 0; p < NPASS; ++p) {
            f2 xv = *(const f2*)&xb[te[p]];     // ds_read2_b32
            f2 mv = *(const f2*)&mrow[te[p]];   // ds_read2_b32
            acc[p] += xv * mv;
        }
        // Own ds_reads of buf j%3 must finish before iter j+1 overwrites it
        // (stage target (j+3)%3 == j%3). Wave-local, cheap.
        asm volatile("s_waitcnt lgkmcnt(0)" ::: "memory");
        __builtin_amdgcn_sched_barrier(0);
    }

    // ---- partials -> own region start (bands done; private to this wave) ----
#pragma unroll
    for (int p = 0; p < NPASS; ++p) {
        int t = p * 128 + 2 * lane;
        *(f2*)&xw[t] = acc[p];   // t <= 1150 < WREG, always in-bounds
    }
    asm volatile("s_waitcnt lgkmcnt(0)" ::: "memory");
    __builtin_amdgcn_s_barrier();   // partials visible

    // ---- 2-way reduce + store ----
    float* orow = out + (size_t)Y * Wp;
#pragma unroll
    for (int q = 0; q < 5; ++q) {
        int t = 2 * (tid + q * 128);
        if (t + 1 < Wp) {
            f2 v = *(const f2*)&lds[t];
            v += *(const f2*)&lds[WREG + t];
            *(f2*)&orow[t] = v;
        } else if (t < Wp) {
            orow[t] = lds[t] + lds[WREG + t];
        }
    }
}

extern "C" void kernel_launch(void* const* d_in, const int* in_sizes, int n_in,
                              void* d_out, int out_size, void* d_ws, size_t ws_size,
                              hipStream_t stream) {
    const float* x = (const float*)d_in[0];      // [1, 28, 1024, 1024]
    const float* mask = (const float*)d_in[1];   // [1024, 1024]
    const float* phi = (const float*)d_in[2];    // [1]
    const float* s_nom = (const float*)d_in[3];  // [28]
    float* out = (float*)d_out;                  // [1, Hp, Wp]

    // One block per output row; Hp <= out_size/W (since Wp >= W).
    const int blocks = out_size / W + 2;
    cassi_v12<<<blocks, 128, 0, stream>>>(x, mask, phi, s_nom, out, out_size);
}